// Round 22
// baseline (226.115 us; speedup 1.0000x reference)
//
#include <hip/hip_runtime.h>
#include <hip/hip_bf16.h>
#include <stdint.h>

// Problem constants
#define B_ 2
#define S_ 2048
#define D_ 1024
#define H_ 16
#define DH_ 64
#define FF_ 4096
#define M_ (B_*S_)   // 4096 tokens

typedef __bf16 bf16;
typedef __bf16 bf16x4 __attribute__((ext_vector_type(4)));
typedef __bf16 bf16x8 __attribute__((ext_vector_type(8)));
typedef float f32x4 __attribute__((ext_vector_type(4)));

#define LOG2E 1.44269504f

__device__ __forceinline__ float fexp2(float x) {
#if __has_builtin(__builtin_amdgcn_exp2f)
  return __builtin_amdgcn_exp2f(x);
#else
  return exp2f(x);
#endif
}

// global -> LDS direct load, 16B per lane. LDS dest = wave-uniform base + lane*16.
__device__ __forceinline__ void gload_lds16(const void* g, void* l) {
  auto gp = reinterpret_cast<const __attribute__((address_space(1))) void*>(
      reinterpret_cast<uintptr_t>(g));
  auto lp = reinterpret_cast<__attribute__((address_space(3))) void*>(
      reinterpret_cast<uintptr_t>(l));
  __builtin_amdgcn_global_load_lds(gp, lp, 16, 0, 0);
}

// ---------------- fused prep: cast + biases + mask + 6 weight transposes ----
__global__ __launch_bounds__(256) void prep_all(
    const float* __restrict__ X, bf16* __restrict__ Xb,
    const float* __restrict__ bq, const float* __restrict__ bk,
    const float* __restrict__ bv, float* __restrict__ bqkv,
    const int* __restrict__ mask, float* __restrict__ Mp,
    const float* __restrict__ Wq, const float* __restrict__ Wk,
    const float* __restrict__ Wv, const float* __restrict__ Wo,
    const float* __restrict__ W1, const float* __restrict__ W2,
    bf16* __restrict__ Wqkvt, bf16* __restrict__ Wot,
    bf16* __restrict__ W1t, bf16* __restrict__ W2t) {
  int bid = blockIdx.x;
  const int tid = threadIdx.x;
  if (bid < 4096) {                       // cast X
    int i = (bid * 256 + tid) * 4;
    float4 v = *(const float4*)(X + i);
    Xb[i+0] = (bf16)v.x; Xb[i+1] = (bf16)v.y;
    Xb[i+2] = (bf16)v.z; Xb[i+3] = (bf16)v.w;
    return;
  }
  bid -= 4096;
  if (bid < 12) {                         // copy3
    int i = bid * 256 + tid;
    bqkv[i] = i < 1024 ? bq[i] : (i < 2048 ? bk[i-1024] : bv[i-2048]);
    return;
  }
  bid -= 12;
  if (bid < 16) {                         // prep_mask (exp2 domain)
    int i = bid * 256 + tid;
    Mp[i] = (-10000.0f * LOG2E) * (float)mask[i];
    return;
  }
  bid -= 16;
  const float* src; bf16* dst; int K, N;
  if (bid < 1024)      { src = Wq; dst = Wqkvt;                     K=1024; N=1024; }
  else if (bid < 2048) { src = Wk; dst = Wqkvt + (size_t)1024*1024; K=1024; N=1024; bid -= 1024; }
  else if (bid < 3072) { src = Wv; dst = Wqkvt + (size_t)2048*1024; K=1024; N=1024; bid -= 2048; }
  else if (bid < 4096) { src = Wo; dst = Wot;                       K=1024; N=1024; bid -= 3072; }
  else if (bid < 8192) { src = W1; dst = W1t;                       K=1024; N=4096; bid -= 4096; }
  else                 { src = W2; dst = W2t;                       K=4096; N=1024; bid -= 8192; }
  __shared__ float t[32][33];
  const int tx = tid & 31, ty = tid >> 5;
  const int nt32 = N >> 5;
  const int n0 = (bid % nt32) * 32, k0 = (bid / nt32) * 32;
#pragma unroll
  for (int i = 0; i < 4; i++)
    t[ty + i*8][tx] = src[(size_t)(k0 + ty + i*8) * N + n0 + tx];
  __syncthreads();
#pragma unroll
  for (int i = 0; i < 4; i++)
    dst[(size_t)(n0 + ty + i*8) * K + k0 + tx] = (bf16)t[tx][ty + i*8];
}
#define PREP_BLOCKS (4096 + 12 + 16 + 4*1024 + 2*4096)

// QKV [4096][3072] (V section) -> Vt [B*H][64][2048], kv'-permuted within
// each 64-chunk (col = (l&15)*4 + (l>>4)), matching attn's P-store layout.
__global__ __launch_bounds__(256) void transpose_v(
    const bf16* __restrict__ QKV, bf16* __restrict__ Vt) {
  __shared__ bf16 t[64][66];
  int bh = blockIdx.x, s0 = blockIdx.y * 64;
  int b = bh >> 4, h = bh & 15;
  int w = threadIdx.x >> 6, l = threadIdx.x & 63;
#pragma unroll
  for (int i = 0; i < 16; i++) {
    int sr = w*16 + i;
    t[sr][l] = QKV[(size_t)(b*S_ + s0 + sr) * 3072 + 2*D_ + h*DH_ + l];
  }
  __syncthreads();
  const int pcol = (l & 15) * 4 + (l >> 4);   // perm(l)
#pragma unroll
  for (int i = 0; i < 16; i++) {
    int dh = w*16 + i;
    Vt[((size_t)(bh*DH_ + dh)) * S_ + s0 + pcol] = t[l][dh];
  }
}

// ---------------- GEMM 128x128 split-K, BK=64, double-buffered -------------
// OUTB: write bf16 partials (reduction in ln_res4); else f32 (ln_res2).
// Bias folded into z==0.
template<int SK, bool OUTB>
__global__ __launch_bounds__(256) void gemm_sk(
    const bf16* __restrict__ A, const bf16* __restrict__ Bt,
    const float* __restrict__ bias, void* __restrict__ Cp,
    int M, int N, int K) {
  __shared__ bf16 As[2][128*64];   // 32KB
  __shared__ bf16 Bs[2][128*64];   // 32KB
  const int tid = threadIdx.x;
  const int w = tid >> 6, l = tid & 63;
  const int wm = w >> 1, wn = w & 1;
  const int r16 = l & 15, g = l >> 4;

  const int gx = gridDim.x, gxy = gx * gridDim.y;
  const int nwg = gxy * SK;
  const int lid = (blockIdx.z * gridDim.y + blockIdx.y) * gx + blockIdx.x;
  const int swz = (lid & 7) * (nwg >> 3) + (lid >> 3);
  const int z = swz / gxy, rem = swz % gxy;
  const int m0 = (rem / gx) * 128, n0 = (rem % gx) * 128;
  const int kc = K / SK, kb = z * kc;

  const int srow = w*8 + (l >> 3);
  const int sch  = ((l & 7) ^ (l >> 3)) * 8;
  const bf16* ag = A + (size_t)(m0 + srow) * K + kb + sch;
  const bf16* bg = Bt + (size_t)(n0 + srow) * K + kb + sch;

  f32x4 acc[4][4];
#pragma unroll
  for (int i = 0; i < 4; i++)
#pragma unroll
    for (int j = 0; j < 4; j++) acc[i][j] = (f32x4){0.f,0.f,0.f,0.f};

#pragma unroll
  for (int q = 0; q < 4; q++) {
    gload_lds16(ag + (size_t)(q*32) * K, &As[0][(q*32 + w*8) * 64]);
    gload_lds16(bg + (size_t)(q*32) * K, &Bs[0][(q*32 + w*8) * 64]);
  }
  asm volatile("s_waitcnt vmcnt(0)" ::: "memory");
  __builtin_amdgcn_s_barrier();
  asm volatile("" ::: "memory");

  const int nt = kc >> 6;
  int cur = 0;
  for (int t = 0; t < nt; ++t) {
    if (t + 1 < nt) {
      const int k0 = (t + 1) * 64;
#pragma unroll
      for (int q = 0; q < 4; q++) {
        gload_lds16(ag + (size_t)(q*32) * K + k0, &As[cur^1][(q*32 + w*8) * 64]);
        gload_lds16(bg + (size_t)(q*32) * K + k0, &Bs[cur^1][(q*32 + w*8) * 64]);
      }
    }
    bf16x8 af[4][2], bfr[4][2];
#pragma unroll
    for (int mi = 0; mi < 4; mi++)
#pragma unroll
      for (int kk = 0; kk < 2; kk++) {
        const int row = wm*64 + mi*16 + r16;
        af[mi][kk] = *(const bf16x8*)&As[cur][row*64 + (((kk*4+g) ^ (row & 7)))*8];
      }
#pragma unroll
    for (int ni = 0; ni < 4; ni++)
#pragma unroll
      for (int kk = 0; kk < 2; kk++) {
        const int row = wn*64 + ni*16 + r16;
        bfr[ni][kk] = *(const bf16x8*)&Bs[cur][row*64 + (((kk*4+g) ^ (row & 7)))*8];
      }
    __builtin_amdgcn_s_setprio(1);
#pragma unroll
    for (int mi = 0; mi < 4; mi++)
#pragma unroll
      for (int ni = 0; ni < 4; ni++)
#pragma unroll
        for (int kk = 0; kk < 2; kk++)
          acc[mi][ni] = __builtin_amdgcn_mfma_f32_16x16x32_bf16(
              af[mi][kk], bfr[ni][kk], acc[mi][ni], 0, 0, 0);
    __builtin_amdgcn_s_setprio(0);

    asm volatile("s_waitcnt vmcnt(0)" ::: "memory");
    __builtin_amdgcn_s_barrier();
    asm volatile("" ::: "memory");
    cur ^= 1;
  }

  float bvs[4];
#pragma unroll
  for (int ni = 0; ni < 4; ni++)
    bvs[ni] = (z == 0) ? bias[n0 + wn*64 + ni*16 + r16] : 0.f;
#pragma unroll
  for (int mi = 0; mi < 4; mi++)
#pragma unroll
    for (int ni = 0; ni < 4; ni++)
#pragma unroll
      for (int r = 0; r < 4; r++) {
        size_t row = (size_t)(m0 + wm*64 + mi*16 + g*4 + r);
        size_t col = (size_t)(n0 + wn*64 + ni*16 + r16);
        float v = acc[mi][ni][r] + bvs[ni];
        if (OUTB) ((bf16*)Cp + (size_t)z * M * N)[row * N + col] = (bf16)v;
        else      ((float*)Cp + (size_t)z * M * N)[row * N + col] = v;
      }
}

// ---------------- GEMM 256x256, BK=64, 8 waves, phased schedule ------------
template<bool RELU>
__global__ __launch_bounds__(512) void gemm256(
    const bf16* __restrict__ A, const bf16* __restrict__ Bt,
    const float* __restrict__ bias, bf16* __restrict__ C,
    int M, int N, int K) {
  __shared__ bf16 As[2][256*64];   // 64KB
  __shared__ bf16 Bs[2][256*64];   // 64KB
  const int tid = threadIdx.x;
  const int w = tid >> 6, l = tid & 63;
  const int wm = w >> 2, wn = w & 3;     // 2 x 4 wave grid, wave tile 128x64
  const int r16 = l & 15, g = l >> 4;

  const int gx = gridDim.x;
  const int nwg = gx * gridDim.y;
  const int lid = blockIdx.y * gx + blockIdx.x;
  const int swz = (lid & 7) * (nwg >> 3) + (lid >> 3);
  const int m0 = (swz / gx) * 256, n0 = (swz % gx) * 256;

  const int srow = w*8 + (l >> 3);
  const int sch  = ((l & 7) ^ (l >> 3)) * 8;
  const bf16* ag = A  + (size_t)(m0 + srow) * K + sch;
  const bf16* bg = Bt + (size_t)(n0 + srow) * K + sch;

  f32x4 acc[8][4];
#pragma unroll
  for (int i = 0; i < 8; i++)
#pragma unroll
    for (int j = 0; j < 4; j++) acc[i][j] = (f32x4){0.f,0.f,0.f,0.f};

#pragma unroll
  for (int q = 0; q < 4; q++) {
    gload_lds16(ag + (size_t)(q*64) * K, &As[0][(q*64 + w*8) * 64]);
    gload_lds16(bg + (size_t)(q*64) * K, &Bs[0][(q*64 + w*8) * 64]);
  }
  asm volatile("s_waitcnt vmcnt(0)" ::: "memory");
  __builtin_amdgcn_s_barrier();
  asm volatile("" ::: "memory");

  const int nt = K >> 6;
  int cur = 0;
  for (int t = 0; t < nt; ++t) {
    if (t + 1 < nt) {
      const size_t k0 = (size_t)(t + 1) << 6;
#pragma unroll
      for (int q = 0; q < 4; q++) {
        gload_lds16(ag + (size_t)(q*64) * K + k0, &As[cur^1][(q*64 + w*8) * 64]);
        gload_lds16(bg + (size_t)(q*64) * K + k0, &Bs[cur^1][(q*64 + w*8) * 64]);
      }
    }

    bf16x8 af[4][2], blo[2][2], bhi[2][2];
#pragma unroll
    for (int mi = 0; mi < 4; mi++)
#pragma unroll
      for (int kk = 0; kk < 2; kk++) {
        const int row = wm*128 + mi*16 + r16;
        af[mi][kk] = *(const bf16x8*)&As[cur][row*64 + (((kk*4+g) ^ (row & 7)))*8];
      }
#pragma unroll
    for (int ni = 0; ni < 2; ni++)
#pragma unroll
      for (int kk = 0; kk < 2; kk++) {
        const int row = wn*64 + ni*16 + r16;
        blo[ni][kk] = *(const bf16x8*)&Bs[cur][row*64 + (((kk*4+g) ^ (row & 7)))*8];
      }
    __builtin_amdgcn_s_setprio(1);
#pragma unroll
    for (int mi = 0; mi < 4; mi++)
#pragma unroll
      for (int ni = 0; ni < 2; ni++)
#pragma unroll
        for (int kk = 0; kk < 2; kk++)
          acc[mi][ni] = __builtin_amdgcn_mfma_f32_16x16x32_bf16(
              af[mi][kk], blo[ni][kk], acc[mi][ni], 0, 0, 0);
    __builtin_amdgcn_s_setprio(0);
#pragma unroll
    for (int ni = 0; ni < 2; ni++)
#pragma unroll
      for (int kk = 0; kk < 2; kk++) {
        const int row = wn*64 + 32 + ni*16 + r16;
        bhi[ni][kk] = *(const bf16x8*)&Bs[cur][row*64 + (((kk*4+g) ^ (row & 7)))*8];
      }
    __builtin_amdgcn_s_setprio(1);
#pragma unroll
    for (int mi = 0; mi < 4; mi++)
#pragma unroll
      for (int ni = 0; ni < 2; ni++)
#pragma unroll
        for (int kk = 0; kk < 2; kk++)
          acc[mi][2+ni] = __builtin_amdgcn_mfma_f32_16x16x32_bf16(
              af[mi][kk], bhi[ni][kk], acc[mi][2+ni], 0, 0, 0);
    __builtin_amdgcn_s_setprio(0);
#pragma unroll
    for (int mi = 0; mi < 4; mi++)
#pragma unroll
      for (int kk = 0; kk < 2; kk++) {
        const int row = wm*128 + 64 + mi*16 + r16;
        af[mi][kk] = *(const bf16x8*)&As[cur][row*64 + (((kk*4+g) ^ (row & 7)))*8];
      }
    __builtin_amdgcn_s_setprio(1);
#pragma unroll
    for (int mi = 0; mi < 4; mi++)
#pragma unroll
      for (int ni = 0; ni < 2; ni++)
#pragma unroll
        for (int kk = 0; kk < 2; kk++)
          acc[4+mi][2+ni] = __builtin_amdgcn_mfma_f32_16x16x32_bf16(
              af[mi][kk], bhi[ni][kk], acc[4+mi][2+ni], 0, 0, 0);
    __builtin_amdgcn_s_setprio(0);
    __builtin_amdgcn_s_setprio(1);
#pragma unroll
    for (int mi = 0; mi < 4; mi++)
#pragma unroll
      for (int ni = 0; ni < 2; ni++)
#pragma unroll
        for (int kk = 0; kk < 2; kk++)
          acc[4+mi][ni] = __builtin_amdgcn_mfma_f32_16x16x32_bf16(
              af[mi][kk], blo[ni][kk], acc[4+mi][ni], 0, 0, 0);
    __builtin_amdgcn_s_setprio(0);

    asm volatile("s_waitcnt vmcnt(0)" ::: "memory");
    __builtin_amdgcn_s_barrier();
    asm volatile("" ::: "memory");
    cur ^= 1;
  }

  float bvs[4];
#pragma unroll
  for (int ni = 0; ni < 4; ni++) bvs[ni] = bias[n0 + wn*64 + ni*16 + r16];
#pragma unroll
  for (int mi = 0; mi < 8; mi++)
#pragma unroll
    for (int ni = 0; ni < 4; ni++)
#pragma unroll
      for (int r = 0; r < 4; r++) {
        float v = acc[mi][ni][r] + bvs[ni];
        if (RELU) v = fmaxf(v, 0.f);
        C[(size_t)(m0 + wm*128 + mi*16 + g*4 + r) * N +
          (n0 + wn*64 + ni*16 + r16)] = (bf16)v;
      }
}

// ---------------- flash attention: 8 waves x 16 q-rows (round-21 winner) ----
__global__ __launch_bounds__(512) void attn(
    const bf16* __restrict__ QKV, const bf16* __restrict__ Vt,
    const float* __restrict__ Mp, bf16* __restrict__ AO) {
  __shared__ bf16 Ks[2][64*64];   // [kv][dh], chunk ^= (kv&7), 16KB
  __shared__ bf16 Vs[2][64*64];   // [dh][kv'], chunk ^= (dh&7), 16KB
  __shared__ bf16 Ps[8][16*72];   // per-wave P, 16 rows, stride 72 (18KB)

  const float SC2 = 0.125f * LOG2E;
  const int bh = blockIdx.x, b = bh >> 4, h = bh & 15;
  const int q0 = blockIdx.y * 128;
  const int tid = threadIdx.x, w = tid >> 6, l = tid & 63;
  const int r16 = l & 15, g = l >> 4;
  const int qw = q0 + w*16;

  bf16x8 qf[2];
#pragma unroll
  for (int kk = 0; kk < 2; kk++)
    qf[kk] = *(const bf16x8*)&QKV[((size_t)(b*S_ + qw + r16))*3072
                                  + h*64 + kk*32 + g*8];

  const int srow = w*8 + (l >> 3);
  const int sch  = (l & 7) ^ (l >> 3);
  const bf16* kg = QKV + ((size_t)(b*S_) + srow)*3072 + 1024 + h*64 + sch*8;
  const bf16* vg = Vt + ((size_t)(bh*64 + srow))*S_ + sch*8;

  f32x4 po[4];
#pragma unroll
  for (int n = 0; n < 4; n++) po[n] = (f32x4){0.f,0.f,0.f,0.f};
  float mrun[4], lsum[4];
#pragma unroll
  for (int r = 0; r < 4; r++) { mrun[r] = -1.0e30f; lsum[r] = 0.f; }

  float madd[4];
#pragma unroll
  for (int ct = 0; ct < 4; ct++) madd[ct] = Mp[b*S_ + ct*16 + r16];
  gload_lds16(kg, &Ks[0][w*512]);
  gload_lds16(vg, &Vs[0][w*512]);

  const int NT = S_/64;
  int cur = 0;
  for (int it = 0; it < NT; ++it) {
    const int kv0 = it * 64;
    if (it + 1 < NT) {
      gload_lds16(kg + (size_t)(kv0 + 64)*3072, &Ks[cur^1][w*512]);
      gload_lds16(vg + kv0 + 64,                &Vs[cur^1][w*512]);
      asm volatile("s_waitcnt vmcnt(2)" ::: "memory");
    } else {
      asm volatile("s_waitcnt vmcnt(0)" ::: "memory");
    }
    __builtin_amdgcn_s_barrier();
    asm volatile("" ::: "memory");

    float sv[4][4];
    __builtin_amdgcn_s_setprio(1);
#pragma unroll
    for (int ct = 0; ct < 4; ct++) {
      const int row = ct*16 + r16;
      bf16x8 kf0 = *(const bf16x8*)&Ks[cur][row*64 + ((g) ^ (row & 7))*8];
      bf16x8 kf1 = *(const bf16x8*)&Ks[cur][row*64 + ((4+g) ^ (row & 7))*8];
      f32x4 s = (f32x4){0.f,0.f,0.f,0.f};
      s = __builtin_amdgcn_mfma_f32_16x16x32_bf16(qf[0], kf0, s, 0, 0, 0);
      s = __builtin_amdgcn_mfma_f32_16x16x32_bf16(qf[1], kf1, s, 0, 0, 0);
#pragma unroll
      for (int r = 0; r < 4; r++) sv[ct][r] = s[r]*SC2 + madd[ct];
    }
    __builtin_amdgcn_s_setprio(0);

    if (it + 1 < NT) {
#pragma unroll
      for (int ct = 0; ct < 4; ct++)
        madd[ct] = Mp[b*S_ + kv0 + 64 + ct*16 + r16];
    }

    float lmax[4];
#pragma unroll
    for (int r = 0; r < 4; r++)
      lmax[r] = fmaxf(fmaxf(sv[0][r], sv[1][r]), fmaxf(sv[2][r], sv[3][r]));
    bool grow = (lmax[0] > mrun[0] + 8.f) | (lmax[1] > mrun[1] + 8.f) |
                (lmax[2] > mrun[2] + 8.f) | (lmax[3] > mrun[3] + 8.f);
    if (__any(grow)) {
#pragma unroll
      for (int r = 0; r < 4; r++) {
        float t = lmax[r];
#pragma unroll
        for (int off = 8; off >= 1; off >>= 1) t = fmaxf(t, __shfl_xor(t, off, 16));
        float mnew = fmaxf(mrun[r], t);
        float sc = fexp2(mrun[r] - mnew);
        mrun[r] = mnew;
        lsum[r] *= sc;
#pragma unroll
        for (int n = 0; n < 4; n++) po[n][r] *= sc;
      }
    }
#pragma unroll
    for (int r = 0; r < 4; r++) {
#pragma unroll
      for (int ct = 0; ct < 4; ct++)
        sv[ct][r] = fexp2(sv[ct][r] - mrun[r]);   // sv becomes P
      lsum[r] += (sv[0][r] + sv[1][r]) + (sv[2][r] + sv[3][r]);
    }

#pragma unroll
    for (int r = 0; r < 4; r++) {
      bf16x4 pk;
#pragma unroll
      for (int ct = 0; ct < 4; ct++) pk[ct] = (bf16)sv[ct][r];
      *(bf16x4*)&Ps[w][(g*4 + r)*72 + r16*4] = pk;
    }
    asm volatile("s_waitcnt lgkmcnt(0)" ::: "memory");

    __builtin_amdgcn_s_setprio(1);
#pragma unroll
    for (int kk = 0; kk < 2; kk++) {
      bf16x8 pa = *(const bf16x8*)&Ps[w][r16*72 + kk*32 + g*8];
#pragma unroll
      for (int n = 0; n < 4; n++) {
        const int row = n*16 + r16;
        bf16x8 vf = *(const bf16x8*)&Vs[cur][row*64 + ((kk*4 + g) ^ (row & 7))*8];
        po[n] = __builtin_amdgcn_mfma_f32_16x16x32_bf16(pa, vf, po[n], 0, 0, 0);
      }
    }
    __builtin_amdgcn_s_setprio(0);

    __builtin_amdgcn_s_barrier();
    asm volatile("" ::: "memory");
    cur ^= 1;
  }

#pragma unroll
  for (int r = 0; r < 4; r++) {
    float t = lsum[r];
#pragma unroll
    for (int off = 8; off >= 1; off >>= 1) t += __shfl_xor(t, off, 16);
    lsum[r] = t;
  }

#pragma unroll
  for (int n = 0; n < 4; n++)
#pragma unroll
    for (int r = 0; r < 4; r++) {
      float v = po[n][r] / lsum[r];
      AO[(size_t)(b*S_ + qw + g*4 + r)*D_ + h*64 + n*16 + r16] = (bf16)v;
    }
}

// ---------------- fused residual + 2-partial f32 reduce + LayerNorm --------
template<bool XF32, bool OUTF32>
__global__ __launch_bounds__(256) void ln_res2(
    const void* __restrict__ xp, const float* __restrict__ p0,
    const float* __restrict__ p1, const float* __restrict__ sc,
    const float* __restrict__ bi, float* __restrict__ y,
    bf16* __restrict__ yb) {
  const int row = blockIdx.x, tid = threadIdx.x;
  const size_t base = (size_t)row * D_;
  float v[4];
  if (XF32) {
    float4 a = ((const float4*)((const float*)xp + base))[tid];
    v[0] = a.x; v[1] = a.y; v[2] = a.z; v[3] = a.w;
  } else {
    bf16x4 a = *(const bf16x4*)&((const bf16*)xp)[base + tid*4];
#pragma unroll
    for (int j = 0; j < 4; j++) v[j] = (float)a[j];
  }
  float4 a0 = ((const float4*)(p0 + base))[tid];
  float4 a1 = ((const float4*)(p1 + base))[tid];
  v[0] += a0.x + a1.x; v[1] += a0.y + a1.y;
  v[2] += a0.z + a1.z; v[3] += a0.w + a1.w;
  float s  = v[0] + v[1] + v[2] + v[3];
  float ss = v[0]*v[0] + v[1]*v[1] + v[2]*v[2] + v[3]*v[3];
#pragma unroll
  for (int off = 32; off >= 1; off >>= 1) {
    s  += __shfl_xor(s, off, 64);
    ss += __shfl_xor(ss, off, 64);
  }
  __shared__ float red[8];
  const int wv = tid >> 6;
  if ((tid & 63) == 0) { red[wv] = s; red[4 + wv] = ss; }
  __syncthreads();
  s  = red[0] + red[1] + red[2] + red[3];
  ss = red[4] + red[5] + red[6] + red[7];
  const float mu  = s * (1.0f / D_);
  const float inv = rsqrtf(ss * (1.0f / D_) - mu*mu + 1e-6f);
  float4 scv = ((const float4*)sc)[tid];
  float4 biv = ((const float4*)bi)[tid];
  float o[4];
  o[0] = (v[0]-mu)*inv*scv.x + biv.x;
  o[1] = (v[1]-mu)*inv*scv.y + biv.y;
  o[2] = (v[2]-mu)*inv*scv.z + biv.z;
  o[3] = (v[3]-mu)*inv*scv.w + biv.w;
  if (OUTF32) {
    ((float4*)(y + base))[tid] = make_float4(o[0], o[1], o[2], o[3]);
  } else {
    bf16x4 ob;
#pragma unroll
    for (int j = 0; j < 4; j++) ob[j] = (bf16)o[j];
    *(bf16x4*)&yb[base + tid*4] = ob;
  }
}

// ---------------- fused residual + 4-partial bf16 reduce + LayerNorm -------
template<bool XF32, bool OUTF32>
__global__ __launch_bounds__(256) void ln_res4(
    const void* __restrict__ xp, const bf16* __restrict__ pb,
    const float* __restrict__ sc, const float* __restrict__ bi,
    float* __restrict__ y, bf16* __restrict__ yb) {
  const int row = blockIdx.x, tid = threadIdx.x;
  const size_t base = (size_t)row * D_;
  float v[4];
  if (XF32) {
    float4 a = ((const float4*)((const float*)xp + base))[tid];
    v[0] = a.x; v[1] = a.y; v[2] = a.z; v[3] = a.w;
  } else {
    bf16x4 a = *(const bf16x4*)&((const bf16*)xp)[base + tid*4];
#pragma unroll
    for (int j = 0; j < 4; j++) v[j] = (float)a[j];
  }
#pragma unroll
  for (int z = 0; z < 4; z++) {
    bf16x4 p = *(const bf16x4*)&pb[(size_t)z*M_*D_ + base + tid*4];
#pragma unroll
    for (int j = 0; j < 4; j++) v[j] += (float)p[j];
  }
  float s  = v[0] + v[1] + v[2] + v[3];
  float ss = v[0]*v[0] + v[1]*v[1] + v[2]*v[2] + v[3]*v[3];
#pragma unroll
  for (int off = 32; off >= 1; off >>= 1) {
    s  += __shfl_xor(s, off, 64);
    ss += __shfl_xor(ss, off, 64);
  }
  __shared__ float red[8];
  const int wv = tid >> 6;
  if ((tid & 63) == 0) { red[wv] = s; red[4 + wv] = ss; }
  __syncthreads();
  s  = red[0] + red[1] + red[2] + red[3];
  ss = red[4] + red[5] + red[6] + red[7];
  const float mu  = s * (1.0f / D_);
  const float inv = rsqrtf(ss * (1.0f / D_) - mu*mu + 1e-6f);
  float4 scv = ((const float4*)sc)[tid];
  float4 biv = ((const float4*)bi)[tid];
  float o[4];
  o[0] = (v[0]-mu)*inv*scv.x + biv.x;
  o[1] = (v[1]-mu)*inv*scv.y + biv.y;
  o[2] = (v[2]-mu)*inv*scv.z + biv.z;
  o[3] = (v[3]-mu)*inv*scv.w + biv.w;
  if (OUTF32) {
    ((float4*)(y + base))[tid] = make_float4(o[0], o[1], o[2], o[3]);
  } else {
    bf16x4 ob;
#pragma unroll
    for (int j = 0; j < 4; j++) ob[j] = (bf16)o[j];
    *(bf16x4*)&yb[base + tid*4] = ob;
  }
}

// ---------------- launch ----------------
extern "C" void kernel_launch(void* const* d_in, const int* in_sizes, int n_in,
                              void* d_out, int out_size, void* d_ws, size_t ws_size,
                              hipStream_t stream) {
  const float* X    = (const float*)d_in[0];
  const int*   mask = (const int*)d_in[1];
  const float* Wq   = (const float*)d_in[2];
  const float* bq   = (const float*)d_in[3];
  const float* Wk   = (const float*)d_in[4];
  const float* bk   = (const float*)d_in[5];
  const float* Wv   = (const float*)d_in[6];
  const float* bv   = (const float*)d_in[7];
  const float* Wo   = (const float*)d_in[8];
  const float* bo   = (const float*)d_in[9];
  const float* ln0s = (const float*)d_in[10];
  const float* ln0b = (const float*)d_in[11];
  const float* W1   = (const float*)d_in[12];
  const float* b1   = (const float*)d_in[13];
  const float* W2   = (const float*)d_in[14];
  const float* b2   = (const float*)d_in[15];
  const float* ln1s = (const float*)d_in[16];
  const float* ln1b = (const float*)d_in[17];
  float* out = (float*)d_out;

  // workspace layout (96 MB), lifetime-checked reuse:
  //  [0,8)    Xb (residual for ln0) -> X1b (in-place, per-row safe)
  //  [8,16)   Wqkvt(6) + Wot(2)
  //  [16,24)  W1t   [24,32) W2t
  //  [32,64)  QKV(24)+Vt(8); AO at [32,40) after attn; FF1 after Wo gemm
  //  [64,96)  bqkv+Mp (head; dead by Wo gemm) -> Wo P0/P1 (f32; dead after
  //           ln0) -> FF2 Pb (4 x 8MB bf16)
  char* ws = (char*)d_ws;
  const size_t MB = 1024 * 1024;
  bf16*  Xb    = (bf16*)(ws + 0);        // 8MB, lives until ln0
  bf16*  X1b   = (bf16*)(ws + 0);        // in-place over Xb at ln0
  bf16*  Wqkvt = (bf16*)(ws + 8*MB);     // 6MB  [3072][1024]
  bf16*  Wot   = (bf16*)(ws + 14*MB);    // 2MB  [1024][1024]
  bf16*  W1t   = (bf16*)(ws + 16*MB);    // 8MB  [4096][1024]
  bf16*  W2t   = (bf16*)(ws + 24*MB);    // 8MB  [1024][4096]
  bf16*  QKV   = (bf16*)(ws + 32*MB);    // 24MB [4096][3072]
  bf16*  AO    = (bf16*)(ws + 32*MB);    // 8MB (QKV dead after attn)
  bf16*  Vt    = (bf16*)(ws + 56*MB);    // 8MB  [32][64][2048]
  bf16*  FF1   = (bf16*)(ws + 32*MB);    // 32MB reuse (AO dead after Wo gemm)
  float* P0    = (float*)(ws + 64*MB);   // 16MB f32 partial 0 (Wo)
  float* P1    = (float*)(ws + 80*MB);   // 16MB f32 partial 1 (Wo)
  bf16*  Pb    = (bf16*)(ws + 64*MB);    // 4 x 8MB bf16 partials (FF2)
  float* bqkv  = (float*)(ws + 64*MB);   // 12KB head (dead by Wo gemm)
  float* Mp    = (float*)(ws + 64*MB + 16384);  // 16KB head (dead after attn)

  prep_all<<<PREP_BLOCKS, 256, 0, stream>>>(
      X, Xb, bq, bk, bv, bqkv, mask, Mp,
      Wq, Wk, Wv, Wo, W1, W2, Wqkvt, Wot, W1t, W2t);

  gemm256<false><<<dim3(3072/256, M_/256), 512, 0, stream>>>(Xb, Wqkvt, bqkv, QKV, M_, 3072, D_);
  transpose_v<<<dim3(32, S_/64), 256, 0, stream>>>(QKV, Vt);
  attn<<<dim3(32, S_/128), 512, 0, stream>>>(QKV, Vt, Mp, AO);
  gemm_sk<2,false><<<dim3(D_/128, M_/128, 2), 256, 0, stream>>>(AO, Wot, bo, P0, M_, D_, D_);
  ln_res2<false,false><<<M_, 256, 0, stream>>>(Xb, P0, P1, ln0s, ln0b, nullptr, X1b);
  gemm256<true><<<dim3(FF_/256, M_/256), 512, 0, stream>>>(X1b, W1t, b1, FF1, M_, FF_, D_);
  gemm_sk<4,true><<<dim3(D_/128, M_/128, 4), 256, 0, stream>>>(FF1, W2t, b2, Pb, M_, D_, FF_);
  ln_res4<false,true><<<M_, 256, 0, stream>>>(X1b, Pb, ln1s, ln1b, out, nullptr);
}

// Round 23
// 218.229 us; speedup vs baseline: 1.0361x; 1.0361x over previous
//
#include <hip/hip_runtime.h>
#include <hip/hip_bf16.h>
#include <stdint.h>

// Problem constants
#define B_ 2
#define S_ 2048
#define D_ 1024
#define H_ 16
#define DH_ 64
#define FF_ 4096
#define M_ (B_*S_)   // 4096 tokens

typedef __bf16 bf16;
typedef __bf16 bf16x4 __attribute__((ext_vector_type(4)));
typedef __bf16 bf16x8 __attribute__((ext_vector_type(8)));
typedef float f32x4 __attribute__((ext_vector_type(4)));

#define LOG2E 1.44269504f

__device__ __forceinline__ float fexp2(float x) {
#if __has_builtin(__builtin_amdgcn_exp2f)
  return __builtin_amdgcn_exp2f(x);
#else
  return exp2f(x);
#endif
}

// global -> LDS direct load, 16B per lane. LDS dest = wave-uniform base + lane*16.
__device__ __forceinline__ void gload_lds16(const void* g, void* l) {
  auto gp = reinterpret_cast<const __attribute__((address_space(1))) void*>(
      reinterpret_cast<uintptr_t>(g));
  auto lp = reinterpret_cast<__attribute__((address_space(3))) void*>(
      reinterpret_cast<uintptr_t>(l));
  __builtin_amdgcn_global_load_lds(gp, lp, 16, 0, 0);
}

// ---------------- fused prep: cast + biases + mask + 6 weight transposes ----
__global__ __launch_bounds__(256) void prep_all(
    const float* __restrict__ X, bf16* __restrict__ Xb,
    const float* __restrict__ bq, const float* __restrict__ bk,
    const float* __restrict__ bv, float* __restrict__ bqkv,
    const int* __restrict__ mask, float* __restrict__ Mp,
    const float* __restrict__ Wq, const float* __restrict__ Wk,
    const float* __restrict__ Wv, const float* __restrict__ Wo,
    const float* __restrict__ W1, const float* __restrict__ W2,
    bf16* __restrict__ Wqkvt, bf16* __restrict__ Wot,
    bf16* __restrict__ W1t, bf16* __restrict__ W2t) {
  int bid = blockIdx.x;
  const int tid = threadIdx.x;
  if (bid < 4096) {                       // cast X
    int i = (bid * 256 + tid) * 4;
    float4 v = *(const float4*)(X + i);
    Xb[i+0] = (bf16)v.x; Xb[i+1] = (bf16)v.y;
    Xb[i+2] = (bf16)v.z; Xb[i+3] = (bf16)v.w;
    return;
  }
  bid -= 4096;
  if (bid < 12) {                         // copy3
    int i = bid * 256 + tid;
    bqkv[i] = i < 1024 ? bq[i] : (i < 2048 ? bk[i-1024] : bv[i-2048]);
    return;
  }
  bid -= 12;
  if (bid < 16) {                         // prep_mask (exp2 domain)
    int i = bid * 256 + tid;
    Mp[i] = (-10000.0f * LOG2E) * (float)mask[i];
    return;
  }
  bid -= 16;
  const float* src; bf16* dst; int K, N;
  if (bid < 1024)      { src = Wq; dst = Wqkvt;                     K=1024; N=1024; }
  else if (bid < 2048) { src = Wk; dst = Wqkvt + (size_t)1024*1024; K=1024; N=1024; bid -= 1024; }
  else if (bid < 3072) { src = Wv; dst = Wqkvt + (size_t)2048*1024; K=1024; N=1024; bid -= 2048; }
  else if (bid < 4096) { src = Wo; dst = Wot;                       K=1024; N=1024; bid -= 3072; }
  else if (bid < 8192) { src = W1; dst = W1t;                       K=1024; N=4096; bid -= 4096; }
  else                 { src = W2; dst = W2t;                       K=4096; N=1024; bid -= 8192; }
  __shared__ float t[32][33];
  const int tx = tid & 31, ty = tid >> 5;
  const int nt32 = N >> 5;
  const int n0 = (bid % nt32) * 32, k0 = (bid / nt32) * 32;
#pragma unroll
  for (int i = 0; i < 4; i++)
    t[ty + i*8][tx] = src[(size_t)(k0 + ty + i*8) * N + n0 + tx];
  __syncthreads();
#pragma unroll
  for (int i = 0; i < 4; i++)
    dst[(size_t)(n0 + ty + i*8) * K + k0 + tx] = (bf16)t[tx][ty + i*8];
}
#define PREP_BLOCKS (4096 + 12 + 16 + 4*1024 + 2*4096)

// QKV [4096][3072] (V section) -> Vt [B*H][64][2048], kv'-permuted within
// each 64-chunk (col = (l&15)*4 + (l>>4)), matching attn's P-store layout.
__global__ __launch_bounds__(256) void transpose_v(
    const bf16* __restrict__ QKV, bf16* __restrict__ Vt) {
  __shared__ bf16 t[64][66];
  int bh = blockIdx.x, s0 = blockIdx.y * 64;
  int b = bh >> 4, h = bh & 15;
  int w = threadIdx.x >> 6, l = threadIdx.x & 63;
#pragma unroll
  for (int i = 0; i < 16; i++) {
    int sr = w*16 + i;
    t[sr][l] = QKV[(size_t)(b*S_ + s0 + sr) * 3072 + 2*D_ + h*DH_ + l];
  }
  __syncthreads();
  const int pcol = (l & 15) * 4 + (l >> 4);   // perm(l)
#pragma unroll
  for (int i = 0; i < 16; i++) {
    int dh = w*16 + i;
    Vt[((size_t)(bh*DH_ + dh)) * S_ + s0 + pcol] = t[l][dh];
  }
}

// ---------------- GEMM 128x128 split-K, BK=64, double-buffered -------------
// f32 partials, bias folded into z==0; reduction fused into ln_res2.
template<int SK>
__global__ __launch_bounds__(256) void gemm_sk(
    const bf16* __restrict__ A, const bf16* __restrict__ Bt,
    const float* __restrict__ bias, float* __restrict__ Cp,
    int M, int N, int K) {
  __shared__ bf16 As[2][128*64];   // 32KB
  __shared__ bf16 Bs[2][128*64];   // 32KB
  const int tid = threadIdx.x;
  const int w = tid >> 6, l = tid & 63;
  const int wm = w >> 1, wn = w & 1;
  const int r16 = l & 15, g = l >> 4;

  const int gx = gridDim.x, gxy = gx * gridDim.y;
  const int nwg = gxy * SK;
  const int lid = (blockIdx.z * gridDim.y + blockIdx.y) * gx + blockIdx.x;
  const int swz = (lid & 7) * (nwg >> 3) + (lid >> 3);
  const int z = swz / gxy, rem = swz % gxy;
  const int m0 = (rem / gx) * 128, n0 = (rem % gx) * 128;
  const int kc = K / SK, kb = z * kc;

  const int srow = w*8 + (l >> 3);
  const int sch  = ((l & 7) ^ (l >> 3)) * 8;
  const bf16* ag = A + (size_t)(m0 + srow) * K + kb + sch;
  const bf16* bg = Bt + (size_t)(n0 + srow) * K + kb + sch;

  f32x4 acc[4][4];
#pragma unroll
  for (int i = 0; i < 4; i++)
#pragma unroll
    for (int j = 0; j < 4; j++) acc[i][j] = (f32x4){0.f,0.f,0.f,0.f};

#pragma unroll
  for (int q = 0; q < 4; q++) {
    gload_lds16(ag + (size_t)(q*32) * K, &As[0][(q*32 + w*8) * 64]);
    gload_lds16(bg + (size_t)(q*32) * K, &Bs[0][(q*32 + w*8) * 64]);
  }
  asm volatile("s_waitcnt vmcnt(0)" ::: "memory");
  __builtin_amdgcn_s_barrier();
  asm volatile("" ::: "memory");

  const int nt = kc >> 6;
  int cur = 0;
  for (int t = 0; t < nt; ++t) {
    if (t + 1 < nt) {
      const int k0 = (t + 1) * 64;
#pragma unroll
      for (int q = 0; q < 4; q++) {
        gload_lds16(ag + (size_t)(q*32) * K + k0, &As[cur^1][(q*32 + w*8) * 64]);
        gload_lds16(bg + (size_t)(q*32) * K + k0, &Bs[cur^1][(q*32 + w*8) * 64]);
      }
    }
    bf16x8 af[4][2], bfr[4][2];
#pragma unroll
    for (int mi = 0; mi < 4; mi++)
#pragma unroll
      for (int kk = 0; kk < 2; kk++) {
        const int row = wm*64 + mi*16 + r16;
        af[mi][kk] = *(const bf16x8*)&As[cur][row*64 + (((kk*4+g) ^ (row & 7)))*8];
      }
#pragma unroll
    for (int ni = 0; ni < 4; ni++)
#pragma unroll
      for (int kk = 0; kk < 2; kk++) {
        const int row = wn*64 + ni*16 + r16;
        bfr[ni][kk] = *(const bf16x8*)&Bs[cur][row*64 + (((kk*4+g) ^ (row & 7)))*8];
      }
    __builtin_amdgcn_s_setprio(1);
#pragma unroll
    for (int mi = 0; mi < 4; mi++)
#pragma unroll
      for (int ni = 0; ni < 4; ni++)
#pragma unroll
        for (int kk = 0; kk < 2; kk++)
          acc[mi][ni] = __builtin_amdgcn_mfma_f32_16x16x32_bf16(
              af[mi][kk], bfr[ni][kk], acc[mi][ni], 0, 0, 0);
    __builtin_amdgcn_s_setprio(0);

    asm volatile("s_waitcnt vmcnt(0)" ::: "memory");
    __builtin_amdgcn_s_barrier();
    asm volatile("" ::: "memory");
    cur ^= 1;
  }

  float* outp = Cp + (size_t)z * M * N;
  float bvs[4];
#pragma unroll
  for (int ni = 0; ni < 4; ni++)
    bvs[ni] = (z == 0) ? bias[n0 + wn*64 + ni*16 + r16] : 0.f;
#pragma unroll
  for (int mi = 0; mi < 4; mi++)
#pragma unroll
    for (int ni = 0; ni < 4; ni++)
#pragma unroll
      for (int r = 0; r < 4; r++) {
        size_t row = (size_t)(m0 + wm*64 + mi*16 + g*4 + r);
        size_t col = (size_t)(n0 + wn*64 + ni*16 + r16);
        outp[row * N + col] = acc[mi][ni][r] + bvs[ni];
      }
}

// ---------------- GEMM 256x256, BK=64, 8 waves, phased schedule ------------
template<bool RELU>
__global__ __launch_bounds__(512) void gemm256(
    const bf16* __restrict__ A, const bf16* __restrict__ Bt,
    const float* __restrict__ bias, bf16* __restrict__ C,
    int M, int N, int K) {
  __shared__ bf16 As[2][256*64];   // 64KB
  __shared__ bf16 Bs[2][256*64];   // 64KB
  const int tid = threadIdx.x;
  const int w = tid >> 6, l = tid & 63;
  const int wm = w >> 2, wn = w & 3;     // 2 x 4 wave grid, wave tile 128x64
  const int r16 = l & 15, g = l >> 4;

  const int gx = gridDim.x;
  const int nwg = gx * gridDim.y;
  const int lid = blockIdx.y * gx + blockIdx.x;
  const int swz = (lid & 7) * (nwg >> 3) + (lid >> 3);
  const int m0 = (swz / gx) * 256, n0 = (swz % gx) * 256;

  const int srow = w*8 + (l >> 3);
  const int sch  = ((l & 7) ^ (l >> 3)) * 8;
  const bf16* ag = A  + (size_t)(m0 + srow) * K + sch;
  const bf16* bg = Bt + (size_t)(n0 + srow) * K + sch;

  f32x4 acc[8][4];
#pragma unroll
  for (int i = 0; i < 8; i++)
#pragma unroll
    for (int j = 0; j < 4; j++) acc[i][j] = (f32x4){0.f,0.f,0.f,0.f};

#pragma unroll
  for (int q = 0; q < 4; q++) {
    gload_lds16(ag + (size_t)(q*64) * K, &As[0][(q*64 + w*8) * 64]);
    gload_lds16(bg + (size_t)(q*64) * K, &Bs[0][(q*64 + w*8) * 64]);
  }
  asm volatile("s_waitcnt vmcnt(0)" ::: "memory");
  __builtin_amdgcn_s_barrier();
  asm volatile("" ::: "memory");

  const int nt = K >> 6;
  int cur = 0;
  for (int t = 0; t < nt; ++t) {
    if (t + 1 < nt) {
      const size_t k0 = (size_t)(t + 1) << 6;
#pragma unroll
      for (int q = 0; q < 4; q++) {
        gload_lds16(ag + (size_t)(q*64) * K + k0, &As[cur^1][(q*64 + w*8) * 64]);
        gload_lds16(bg + (size_t)(q*64) * K + k0, &Bs[cur^1][(q*64 + w*8) * 64]);
      }
    }

    bf16x8 af[4][2], blo[2][2], bhi[2][2];
#pragma unroll
    for (int mi = 0; mi < 4; mi++)
#pragma unroll
      for (int kk = 0; kk < 2; kk++) {
        const int row = wm*128 + mi*16 + r16;
        af[mi][kk] = *(const bf16x8*)&As[cur][row*64 + (((kk*4+g) ^ (row & 7)))*8];
      }
#pragma unroll
    for (int ni = 0; ni < 2; ni++)
#pragma unroll
      for (int kk = 0; kk < 2; kk++) {
        const int row = wn*64 + ni*16 + r16;
        blo[ni][kk] = *(const bf16x8*)&Bs[cur][row*64 + (((kk*4+g) ^ (row & 7)))*8];
      }
    __builtin_amdgcn_s_setprio(1);
#pragma unroll
    for (int mi = 0; mi < 4; mi++)
#pragma unroll
      for (int ni = 0; ni < 2; ni++)
#pragma unroll
        for (int kk = 0; kk < 2; kk++)
          acc[mi][ni] = __builtin_amdgcn_mfma_f32_16x16x32_bf16(
              af[mi][kk], blo[ni][kk], acc[mi][ni], 0, 0, 0);
    __builtin_amdgcn_s_setprio(0);
#pragma unroll
    for (int ni = 0; ni < 2; ni++)
#pragma unroll
      for (int kk = 0; kk < 2; kk++) {
        const int row = wn*64 + 32 + ni*16 + r16;
        bhi[ni][kk] = *(const bf16x8*)&Bs[cur][row*64 + (((kk*4+g) ^ (row & 7)))*8];
      }
    __builtin_amdgcn_s_setprio(1);
#pragma unroll
    for (int mi = 0; mi < 4; mi++)
#pragma unroll
      for (int ni = 0; ni < 2; ni++)
#pragma unroll
        for (int kk = 0; kk < 2; kk++)
          acc[mi][2+ni] = __builtin_amdgcn_mfma_f32_16x16x32_bf16(
              af[mi][kk], bhi[ni][kk], acc[mi][2+ni], 0, 0, 0);
    __builtin_amdgcn_s_setprio(0);
#pragma unroll
    for (int mi = 0; mi < 4; mi++)
#pragma unroll
      for (int kk = 0; kk < 2; kk++) {
        const int row = wm*128 + 64 + mi*16 + r16;
        af[mi][kk] = *(const bf16x8*)&As[cur][row*64 + (((kk*4+g) ^ (row & 7)))*8];
      }
    __builtin_amdgcn_s_setprio(1);
#pragma unroll
    for (int mi = 0; mi < 4; mi++)
#pragma unroll
      for (int ni = 0; ni < 2; ni++)
#pragma unroll
        for (int kk = 0; kk < 2; kk++)
          acc[4+mi][2+ni] = __builtin_amdgcn_mfma_f32_16x16x32_bf16(
              af[mi][kk], bhi[ni][kk], acc[4+mi][2+ni], 0, 0, 0);
    __builtin_amdgcn_s_setprio(0);
    __builtin_amdgcn_s_setprio(1);
#pragma unroll
    for (int mi = 0; mi < 4; mi++)
#pragma unroll
      for (int ni = 0; ni < 2; ni++)
#pragma unroll
        for (int kk = 0; kk < 2; kk++)
          acc[4+mi][ni] = __builtin_amdgcn_mfma_f32_16x16x32_bf16(
              af[mi][kk], blo[ni][kk], acc[4+mi][ni], 0, 0, 0);
    __builtin_amdgcn_s_setprio(0);

    asm volatile("s_waitcnt vmcnt(0)" ::: "memory");
    __builtin_amdgcn_s_barrier();
    asm volatile("" ::: "memory");
    cur ^= 1;
  }

  float bvs[4];
#pragma unroll
  for (int ni = 0; ni < 4; ni++) bvs[ni] = bias[n0 + wn*64 + ni*16 + r16];
#pragma unroll
  for (int mi = 0; mi < 8; mi++)
#pragma unroll
    for (int ni = 0; ni < 4; ni++)
#pragma unroll
      for (int r = 0; r < 4; r++) {
        float v = acc[mi][ni][r] + bvs[ni];
        if (RELU) v = fmaxf(v, 0.f);
        C[(size_t)(m0 + wm*128 + mi*16 + g*4 + r) * N +
          (n0 + wn*64 + ni*16 + r16)] = (bf16)v;
      }
}

// ---------------- flash attention: 8 waves x 16 q-rows (round-21 winner) ----
__global__ __launch_bounds__(512) void attn(
    const bf16* __restrict__ QKV, const bf16* __restrict__ Vt,
    const float* __restrict__ Mp, bf16* __restrict__ AO) {
  __shared__ bf16 Ks[2][64*64];   // [kv][dh], chunk ^= (kv&7), 16KB
  __shared__ bf16 Vs[2][64*64];   // [dh][kv'], chunk ^= (dh&7), 16KB
  __shared__ bf16 Ps[8][16*72];   // per-wave P, 16 rows, stride 72 (18KB)

  const float SC2 = 0.125f * LOG2E;
  const int bh = blockIdx.x, b = bh >> 4, h = bh & 15;
  const int q0 = blockIdx.y * 128;
  const int tid = threadIdx.x, w = tid >> 6, l = tid & 63;
  const int r16 = l & 15, g = l >> 4;
  const int qw = q0 + w*16;

  bf16x8 qf[2];
#pragma unroll
  for (int kk = 0; kk < 2; kk++)
    qf[kk] = *(const bf16x8*)&QKV[((size_t)(b*S_ + qw + r16))*3072
                                  + h*64 + kk*32 + g*8];

  const int srow = w*8 + (l >> 3);
  const int sch  = (l & 7) ^ (l >> 3);
  const bf16* kg = QKV + ((size_t)(b*S_) + srow)*3072 + 1024 + h*64 + sch*8;
  const bf16* vg = Vt + ((size_t)(bh*64 + srow))*S_ + sch*8;

  f32x4 po[4];
#pragma unroll
  for (int n = 0; n < 4; n++) po[n] = (f32x4){0.f,0.f,0.f,0.f};
  float mrun[4], lsum[4];
#pragma unroll
  for (int r = 0; r < 4; r++) { mrun[r] = -1.0e30f; lsum[r] = 0.f; }

  float madd[4];
#pragma unroll
  for (int ct = 0; ct < 4; ct++) madd[ct] = Mp[b*S_ + ct*16 + r16];
  gload_lds16(kg, &Ks[0][w*512]);
  gload_lds16(vg, &Vs[0][w*512]);

  const int NT = S_/64;
  int cur = 0;
  for (int it = 0; it < NT; ++it) {
    const int kv0 = it * 64;
    if (it + 1 < NT) {
      gload_lds16(kg + (size_t)(kv0 + 64)*3072, &Ks[cur^1][w*512]);
      gload_lds16(vg + kv0 + 64,                &Vs[cur^1][w*512]);
      asm volatile("s_waitcnt vmcnt(2)" ::: "memory");
    } else {
      asm volatile("s_waitcnt vmcnt(0)" ::: "memory");
    }
    __builtin_amdgcn_s_barrier();
    asm volatile("" ::: "memory");

    float sv[4][4];
    __builtin_amdgcn_s_setprio(1);
#pragma unroll
    for (int ct = 0; ct < 4; ct++) {
      const int row = ct*16 + r16;
      bf16x8 kf0 = *(const bf16x8*)&Ks[cur][row*64 + ((g) ^ (row & 7))*8];
      bf16x8 kf1 = *(const bf16x8*)&Ks[cur][row*64 + ((4+g) ^ (row & 7))*8];
      f32x4 s = (f32x4){0.f,0.f,0.f,0.f};
      s = __builtin_amdgcn_mfma_f32_16x16x32_bf16(qf[0], kf0, s, 0, 0, 0);
      s = __builtin_amdgcn_mfma_f32_16x16x32_bf16(qf[1], kf1, s, 0, 0, 0);
#pragma unroll
      for (int r = 0; r < 4; r++) sv[ct][r] = s[r]*SC2 + madd[ct];
    }
    __builtin_amdgcn_s_setprio(0);

    if (it + 1 < NT) {
#pragma unroll
      for (int ct = 0; ct < 4; ct++)
        madd[ct] = Mp[b*S_ + kv0 + 64 + ct*16 + r16];
    }

    float lmax[4];
#pragma unroll
    for (int r = 0; r < 4; r++)
      lmax[r] = fmaxf(fmaxf(sv[0][r], sv[1][r]), fmaxf(sv[2][r], sv[3][r]));
    bool grow = (lmax[0] > mrun[0] + 8.f) | (lmax[1] > mrun[1] + 8.f) |
                (lmax[2] > mrun[2] + 8.f) | (lmax[3] > mrun[3] + 8.f);
    if (__any(grow)) {
#pragma unroll
      for (int r = 0; r < 4; r++) {
        float t = lmax[r];
#pragma unroll
        for (int off = 8; off >= 1; off >>= 1) t = fmaxf(t, __shfl_xor(t, off, 16));
        float mnew = fmaxf(mrun[r], t);
        float sc = fexp2(mrun[r] - mnew);
        mrun[r] = mnew;
        lsum[r] *= sc;
#pragma unroll
        for (int n = 0; n < 4; n++) po[n][r] *= sc;
      }
    }
#pragma unroll
    for (int r = 0; r < 4; r++) {
#pragma unroll
      for (int ct = 0; ct < 4; ct++)
        sv[ct][r] = fexp2(sv[ct][r] - mrun[r]);   // sv becomes P
      lsum[r] += (sv[0][r] + sv[1][r]) + (sv[2][r] + sv[3][r]);
    }

#pragma unroll
    for (int r = 0; r < 4; r++) {
      bf16x4 pk;
#pragma unroll
      for (int ct = 0; ct < 4; ct++) pk[ct] = (bf16)sv[ct][r];
      *(bf16x4*)&Ps[w][(g*4 + r)*72 + r16*4] = pk;
    }
    asm volatile("s_waitcnt lgkmcnt(0)" ::: "memory");

    __builtin_amdgcn_s_setprio(1);
#pragma unroll
    for (int kk = 0; kk < 2; kk++) {
      bf16x8 pa = *(const bf16x8*)&Ps[w][r16*72 + kk*32 + g*8];
#pragma unroll
      for (int n = 0; n < 4; n++) {
        const int row = n*16 + r16;
        bf16x8 vf = *(const bf16x8*)&Vs[cur][row*64 + ((kk*4 + g) ^ (row & 7))*8];
        po[n] = __builtin_amdgcn_mfma_f32_16x16x32_bf16(pa, vf, po[n], 0, 0, 0);
      }
    }
    __builtin_amdgcn_s_setprio(0);

    __builtin_amdgcn_s_barrier();
    asm volatile("" ::: "memory");
    cur ^= 1;
  }

#pragma unroll
  for (int r = 0; r < 4; r++) {
    float t = lsum[r];
#pragma unroll
    for (int off = 8; off >= 1; off >>= 1) t += __shfl_xor(t, off, 16);
    lsum[r] = t;
  }

#pragma unroll
  for (int n = 0; n < 4; n++)
#pragma unroll
    for (int r = 0; r < 4; r++) {
      float v = po[n][r] / lsum[r];
      AO[(size_t)(b*S_ + qw + g*4 + r)*D_ + h*64 + n*16 + r16] = (bf16)v;
    }
}

// ---------------- fused residual + 2-partial f32 reduce + LayerNorm --------
template<bool XF32, bool OUTF32>
__global__ __launch_bounds__(256) void ln_res2(
    const void* __restrict__ xp, const float* __restrict__ p0,
    const float* __restrict__ p1, const float* __restrict__ sc,
    const float* __restrict__ bi, float* __restrict__ y,
    bf16* __restrict__ yb) {
  const int row = blockIdx.x, tid = threadIdx.x;
  const size_t base = (size_t)row * D_;
  float v[4];
  if (XF32) {
    float4 a = ((const float4*)((const float*)xp + base))[tid];
    v[0] = a.x; v[1] = a.y; v[2] = a.z; v[3] = a.w;
  } else {
    bf16x4 a = *(const bf16x4*)&((const bf16*)xp)[base + tid*4];
#pragma unroll
    for (int j = 0; j < 4; j++) v[j] = (float)a[j];
  }
  float4 a0 = ((const float4*)(p0 + base))[tid];
  float4 a1 = ((const float4*)(p1 + base))[tid];
  v[0] += a0.x + a1.x; v[1] += a0.y + a1.y;
  v[2] += a0.z + a1.z; v[3] += a0.w + a1.w;
  float s  = v[0] + v[1] + v[2] + v[3];
  float ss = v[0]*v[0] + v[1]*v[1] + v[2]*v[2] + v[3]*v[3];
#pragma unroll
  for (int off = 32; off >= 1; off >>= 1) {
    s  += __shfl_xor(s, off, 64);
    ss += __shfl_xor(ss, off, 64);
  }
  __shared__ float red[8];
  const int wv = tid >> 6;
  if ((tid & 63) == 0) { red[wv] = s; red[4 + wv] = ss; }
  __syncthreads();
  s  = red[0] + red[1] + red[2] + red[3];
  ss = red[4] + red[5] + red[6] + red[7];
  const float mu  = s * (1.0f / D_);
  const float inv = rsqrtf(ss * (1.0f / D_) - mu*mu + 1e-6f);
  float4 scv = ((const float4*)sc)[tid];
  float4 biv = ((const float4*)bi)[tid];
  float o[4];
  o[0] = (v[0]-mu)*inv*scv.x + biv.x;
  o[1] = (v[1]-mu)*inv*scv.y + biv.y;
  o[2] = (v[2]-mu)*inv*scv.z + biv.z;
  o[3] = (v[3]-mu)*inv*scv.w + biv.w;
  if (OUTF32) {
    ((float4*)(y + base))[tid] = make_float4(o[0], o[1], o[2], o[3]);
  } else {
    bf16x4 ob;
#pragma unroll
    for (int j = 0; j < 4; j++) ob[j] = (bf16)o[j];
    *(bf16x4*)&yb[base + tid*4] = ob;
  }
}

// ---------------- launch ----------------
extern "C" void kernel_launch(void* const* d_in, const int* in_sizes, int n_in,
                              void* d_out, int out_size, void* d_ws, size_t ws_size,
                              hipStream_t stream) {
  const float* X    = (const float*)d_in[0];
  const int*   mask = (const int*)d_in[1];
  const float* Wq   = (const float*)d_in[2];
  const float* bq   = (const float*)d_in[3];
  const float* Wk   = (const float*)d_in[4];
  const float* bk   = (const float*)d_in[5];
  const float* Wv   = (const float*)d_in[6];
  const float* bv   = (const float*)d_in[7];
  const float* Wo   = (const float*)d_in[8];
  const float* bo   = (const float*)d_in[9];
  const float* ln0s = (const float*)d_in[10];
  const float* ln0b = (const float*)d_in[11];
  const float* W1   = (const float*)d_in[12];
  const float* b1   = (const float*)d_in[13];
  const float* W2   = (const float*)d_in[14];
  const float* b2   = (const float*)d_in[15];
  const float* ln1s = (const float*)d_in[16];
  const float* ln1b = (const float*)d_in[17];
  float* out = (float*)d_out;

  // workspace layout (96 MB), lifetime-checked reuse:
  //  [0,8)    Xb (residual for ln0) -> X1b (in-place, per-row safe)
  //  [8,16)   Wqkvt(6) + Wot(2)
  //  [16,24)  W1t   [24,32) W2t
  //  [32,64)  QKV(24)+Vt(8); AO at [32,40) after attn; FF1 after Wo gemm
  //  [64,80)  bqkv+Mp (head) -> WoP0 -> F2P0
  //  [80,96)  WoP1 -> F2P1
  char* ws = (char*)d_ws;
  const size_t MB = 1024 * 1024;
  bf16*  Xb    = (bf16*)(ws + 0);        // 8MB, lives until ln0
  bf16*  X1b   = (bf16*)(ws + 0);        // in-place over Xb at ln0
  bf16*  Wqkvt = (bf16*)(ws + 8*MB);     // 6MB  [3072][1024]
  bf16*  Wot   = (bf16*)(ws + 14*MB);    // 2MB  [1024][1024]
  bf16*  W1t   = (bf16*)(ws + 16*MB);    // 8MB  [4096][1024]
  bf16*  W2t   = (bf16*)(ws + 24*MB);    // 8MB  [1024][4096]
  bf16*  QKV   = (bf16*)(ws + 32*MB);    // 24MB [4096][3072]
  bf16*  AO    = (bf16*)(ws + 32*MB);    // 8MB (QKV dead after attn)
  bf16*  Vt    = (bf16*)(ws + 56*MB);    // 8MB  [32][64][2048]
  bf16*  FF1   = (bf16*)(ws + 32*MB);    // 32MB reuse (AO dead after Wo gemm)
  float* P0    = (float*)(ws + 64*MB);   // 16MB partial 0 (Wo then FF2)
  float* P1    = (float*)(ws + 80*MB);   // 16MB partial 1
  float* bqkv  = (float*)(ws + 64*MB);   // 12KB head of P0 (dead by Wo gemm)
  float* Mp    = (float*)(ws + 64*MB + 16384);  // 16KB head of P0

  prep_all<<<PREP_BLOCKS, 256, 0, stream>>>(
      X, Xb, bq, bk, bv, bqkv, mask, Mp,
      Wq, Wk, Wv, Wo, W1, W2, Wqkvt, Wot, W1t, W2t);

  gemm256<false><<<dim3(3072/256, M_/256), 512, 0, stream>>>(Xb, Wqkvt, bqkv, QKV, M_, 3072, D_);
  transpose_v<<<dim3(32, S_/64), 256, 0, stream>>>(QKV, Vt);
  attn<<<dim3(32, S_/128), 512, 0, stream>>>(QKV, Vt, Mp, AO);
  gemm_sk<2><<<dim3(D_/128, M_/128, 2), 256, 0, stream>>>(AO, Wot, bo, P0, M_, D_, D_);
  ln_res2<false,false><<<M_, 256, 0, stream>>>(Xb, P0, P1, ln0s, ln0b, nullptr, X1b);
  gemm256<true><<<dim3(FF_/256, M_/256), 512, 0, stream>>>(X1b, W1t, b1, FF1, M_, FF_, D_);
  gemm_sk<2><<<dim3(D_/128, M_/128, 2), 256, 0, stream>>>(FF1, W2t, b2, P0, M_, D_, FF_);
  ln_res2<false,true><<<M_, 256, 0, stream>>>(X1b, P0, P1, ln1s, ln1b, out, nullptr);
}

// Round 24
// 213.531 us; speedup vs baseline: 1.0589x; 1.0220x over previous
//
#include <hip/hip_runtime.h>
#include <hip/hip_bf16.h>
#include <stdint.h>

// Problem constants
#define B_ 2
#define S_ 2048
#define D_ 1024
#define H_ 16
#define DH_ 64
#define FF_ 4096
#define M_ (B_*S_)   // 4096 tokens

typedef __bf16 bf16;
typedef __bf16 bf16x4 __attribute__((ext_vector_type(4)));
typedef __bf16 bf16x8 __attribute__((ext_vector_type(8)));
typedef float f32x4 __attribute__((ext_vector_type(4)));

#define LOG2E 1.44269504f

__device__ __forceinline__ float fexp2(float x) {
#if __has_builtin(__builtin_amdgcn_exp2f)
  return __builtin_amdgcn_exp2f(x);
#else
  return exp2f(x);
#endif
}

// global -> LDS direct load, 16B per lane. LDS dest = wave-uniform base + lane*16.
__device__ __forceinline__ void gload_lds16(const void* g, void* l) {
  auto gp = reinterpret_cast<const __attribute__((address_space(1))) void*>(
      reinterpret_cast<uintptr_t>(g));
  auto lp = reinterpret_cast<__attribute__((address_space(3))) void*>(
      reinterpret_cast<uintptr_t>(l));
  __builtin_amdgcn_global_load_lds(gp, lp, 16, 0, 0);
}

// ---------------- fused prep: cast + biases + mask + 6 weight transposes ----
__global__ __launch_bounds__(256) void prep_all(
    const float* __restrict__ X, bf16* __restrict__ Xb,
    const float* __restrict__ bq, const float* __restrict__ bk,
    const float* __restrict__ bv, float* __restrict__ bqkv,
    const int* __restrict__ mask, float* __restrict__ Mp,
    const float* __restrict__ Wq, const float* __restrict__ Wk,
    const float* __restrict__ Wv, const float* __restrict__ Wo,
    const float* __restrict__ W1, const float* __restrict__ W2,
    bf16* __restrict__ Wqkvt, bf16* __restrict__ Wot,
    bf16* __restrict__ W1t, bf16* __restrict__ W2t) {
  int bid = blockIdx.x;
  const int tid = threadIdx.x;
  if (bid < 4096) {                       // cast X
    int i = (bid * 256 + tid) * 4;
    float4 v = *(const float4*)(X + i);
    Xb[i+0] = (bf16)v.x; Xb[i+1] = (bf16)v.y;
    Xb[i+2] = (bf16)v.z; Xb[i+3] = (bf16)v.w;
    return;
  }
  bid -= 4096;
  if (bid < 12) {                         // copy3
    int i = bid * 256 + tid;
    bqkv[i] = i < 1024 ? bq[i] : (i < 2048 ? bk[i-1024] : bv[i-2048]);
    return;
  }
  bid -= 12;
  if (bid < 16) {                         // prep_mask (exp2 domain)
    int i = bid * 256 + tid;
    Mp[i] = (-10000.0f * LOG2E) * (float)mask[i];
    return;
  }
  bid -= 16;
  const float* src; bf16* dst; int K, N;
  if (bid < 1024)      { src = Wq; dst = Wqkvt;                     K=1024; N=1024; }
  else if (bid < 2048) { src = Wk; dst = Wqkvt + (size_t)1024*1024; K=1024; N=1024; bid -= 1024; }
  else if (bid < 3072) { src = Wv; dst = Wqkvt + (size_t)2048*1024; K=1024; N=1024; bid -= 2048; }
  else if (bid < 4096) { src = Wo; dst = Wot;                       K=1024; N=1024; bid -= 3072; }
  else if (bid < 8192) { src = W1; dst = W1t;                       K=1024; N=4096; bid -= 4096; }
  else                 { src = W2; dst = W2t;                       K=4096; N=1024; bid -= 8192; }
  __shared__ float t[32][33];
  const int tx = tid & 31, ty = tid >> 5;
  const int nt32 = N >> 5;
  const int n0 = (bid % nt32) * 32, k0 = (bid / nt32) * 32;
#pragma unroll
  for (int i = 0; i < 4; i++)
    t[ty + i*8][tx] = src[(size_t)(k0 + ty + i*8) * N + n0 + tx];
  __syncthreads();
#pragma unroll
  for (int i = 0; i < 4; i++)
    dst[(size_t)(n0 + ty + i*8) * K + k0 + tx] = (bf16)t[tx][ty + i*8];
}
#define PREP_BLOCKS (4096 + 12 + 16 + 4*1024 + 2*4096)

// QKV [4096][3072] (V section) -> Vt [B*H][64][2048], kv'-permuted within
// each 64-chunk (col = (l&15)*4 + (l>>4)), matching attn's P-store layout.
__global__ __launch_bounds__(256) void transpose_v(
    const bf16* __restrict__ QKV, bf16* __restrict__ Vt) {
  __shared__ bf16 t[64][66];
  int bh = blockIdx.x, s0 = blockIdx.y * 64;
  int b = bh >> 4, h = bh & 15;
  int w = threadIdx.x >> 6, l = threadIdx.x & 63;
#pragma unroll
  for (int i = 0; i < 16; i++) {
    int sr = w*16 + i;
    t[sr][l] = QKV[(size_t)(b*S_ + s0 + sr) * 3072 + 2*D_ + h*DH_ + l];
  }
  __syncthreads();
  const int pcol = (l & 15) * 4 + (l >> 4);   // perm(l)
#pragma unroll
  for (int i = 0; i < 16; i++) {
    int dh = w*16 + i;
    Vt[((size_t)(bh*DH_ + dh)) * S_ + s0 + pcol] = t[l][dh];
  }
}

// ---------------- GEMM 128x128 split-K, BK=64, double-buffered -------------
// OUTB: bf16 partials (halved traffic; r12/r22-proven numerics). Bias in z==0.
template<int SK, bool OUTB>
__global__ __launch_bounds__(256) void gemm_sk(
    const bf16* __restrict__ A, const bf16* __restrict__ Bt,
    const float* __restrict__ bias, void* __restrict__ Cp,
    int M, int N, int K) {
  __shared__ bf16 As[2][128*64];   // 32KB
  __shared__ bf16 Bs[2][128*64];   // 32KB
  const int tid = threadIdx.x;
  const int w = tid >> 6, l = tid & 63;
  const int wm = w >> 1, wn = w & 1;
  const int r16 = l & 15, g = l >> 4;

  const int gx = gridDim.x, gxy = gx * gridDim.y;
  const int nwg = gxy * SK;
  const int lid = (blockIdx.z * gridDim.y + blockIdx.y) * gx + blockIdx.x;
  const int swz = (lid & 7) * (nwg >> 3) + (lid >> 3);
  const int z = swz / gxy, rem = swz % gxy;
  const int m0 = (rem / gx) * 128, n0 = (rem % gx) * 128;
  const int kc = K / SK, kb = z * kc;

  const int srow = w*8 + (l >> 3);
  const int sch  = ((l & 7) ^ (l >> 3)) * 8;
  const bf16* ag = A + (size_t)(m0 + srow) * K + kb + sch;
  const bf16* bg = Bt + (size_t)(n0 + srow) * K + kb + sch;

  f32x4 acc[4][4];
#pragma unroll
  for (int i = 0; i < 4; i++)
#pragma unroll
    for (int j = 0; j < 4; j++) acc[i][j] = (f32x4){0.f,0.f,0.f,0.f};

#pragma unroll
  for (int q = 0; q < 4; q++) {
    gload_lds16(ag + (size_t)(q*32) * K, &As[0][(q*32 + w*8) * 64]);
    gload_lds16(bg + (size_t)(q*32) * K, &Bs[0][(q*32 + w*8) * 64]);
  }
  asm volatile("s_waitcnt vmcnt(0)" ::: "memory");
  __builtin_amdgcn_s_barrier();
  asm volatile("" ::: "memory");

  const int nt = kc >> 6;
  int cur = 0;
  for (int t = 0; t < nt; ++t) {
    if (t + 1 < nt) {
      const int k0 = (t + 1) * 64;
#pragma unroll
      for (int q = 0; q < 4; q++) {
        gload_lds16(ag + (size_t)(q*32) * K + k0, &As[cur^1][(q*32 + w*8) * 64]);
        gload_lds16(bg + (size_t)(q*32) * K + k0, &Bs[cur^1][(q*32 + w*8) * 64]);
      }
    }
    bf16x8 af[4][2], bfr[4][2];
#pragma unroll
    for (int mi = 0; mi < 4; mi++)
#pragma unroll
      for (int kk = 0; kk < 2; kk++) {
        const int row = wm*64 + mi*16 + r16;
        af[mi][kk] = *(const bf16x8*)&As[cur][row*64 + (((kk*4+g) ^ (row & 7)))*8];
      }
#pragma unroll
    for (int ni = 0; ni < 4; ni++)
#pragma unroll
      for (int kk = 0; kk < 2; kk++) {
        const int row = wn*64 + ni*16 + r16;
        bfr[ni][kk] = *(const bf16x8*)&Bs[cur][row*64 + (((kk*4+g) ^ (row & 7)))*8];
      }
    __builtin_amdgcn_s_setprio(1);
#pragma unroll
    for (int mi = 0; mi < 4; mi++)
#pragma unroll
      for (int ni = 0; ni < 4; ni++)
#pragma unroll
        for (int kk = 0; kk < 2; kk++)
          acc[mi][ni] = __builtin_amdgcn_mfma_f32_16x16x32_bf16(
              af[mi][kk], bfr[ni][kk], acc[mi][ni], 0, 0, 0);
    __builtin_amdgcn_s_setprio(0);

    asm volatile("s_waitcnt vmcnt(0)" ::: "memory");
    __builtin_amdgcn_s_barrier();
    asm volatile("" ::: "memory");
    cur ^= 1;
  }

  float bvs[4];
#pragma unroll
  for (int ni = 0; ni < 4; ni++)
    bvs[ni] = (z == 0) ? bias[n0 + wn*64 + ni*16 + r16] : 0.f;
#pragma unroll
  for (int mi = 0; mi < 4; mi++)
#pragma unroll
    for (int ni = 0; ni < 4; ni++)
#pragma unroll
      for (int r = 0; r < 4; r++) {
        size_t row = (size_t)(m0 + wm*64 + mi*16 + g*4 + r);
        size_t col = (size_t)(n0 + wn*64 + ni*16 + r16);
        float v = acc[mi][ni][r] + bvs[ni];
        if (OUTB) ((bf16*)Cp + (size_t)z * M * N)[row * N + col] = (bf16)v;
        else      ((float*)Cp + (size_t)z * M * N)[row * N + col] = v;
      }
}

// ---------------- GEMM 256x256, BK=64, 8 waves, phased schedule ------------
template<bool RELU>
__global__ __launch_bounds__(512) void gemm256(
    const bf16* __restrict__ A, const bf16* __restrict__ Bt,
    const float* __restrict__ bias, bf16* __restrict__ C,
    int M, int N, int K) {
  __shared__ bf16 As[2][256*64];   // 64KB
  __shared__ bf16 Bs[2][256*64];   // 64KB
  const int tid = threadIdx.x;
  const int w = tid >> 6, l = tid & 63;
  const int wm = w >> 2, wn = w & 3;     // 2 x 4 wave grid, wave tile 128x64
  const int r16 = l & 15, g = l >> 4;

  const int gx = gridDim.x;
  const int nwg = gx * gridDim.y;
  const int lid = blockIdx.y * gx + blockIdx.x;
  const int swz = (lid & 7) * (nwg >> 3) + (lid >> 3);
  const int m0 = (swz / gx) * 256, n0 = (swz % gx) * 256;

  const int srow = w*8 + (l >> 3);
  const int sch  = ((l & 7) ^ (l >> 3)) * 8;
  const bf16* ag = A  + (size_t)(m0 + srow) * K + sch;
  const bf16* bg = Bt + (size_t)(n0 + srow) * K + sch;

  f32x4 acc[8][4];
#pragma unroll
  for (int i = 0; i < 8; i++)
#pragma unroll
    for (int j = 0; j < 4; j++) acc[i][j] = (f32x4){0.f,0.f,0.f,0.f};

#pragma unroll
  for (int q = 0; q < 4; q++) {
    gload_lds16(ag + (size_t)(q*64) * K, &As[0][(q*64 + w*8) * 64]);
    gload_lds16(bg + (size_t)(q*64) * K, &Bs[0][(q*64 + w*8) * 64]);
  }
  asm volatile("s_waitcnt vmcnt(0)" ::: "memory");
  __builtin_amdgcn_s_barrier();
  asm volatile("" ::: "memory");

  const int nt = K >> 6;
  int cur = 0;
  for (int t = 0; t < nt; ++t) {
    if (t + 1 < nt) {
      const size_t k0 = (size_t)(t + 1) << 6;
#pragma unroll
      for (int q = 0; q < 4; q++) {
        gload_lds16(ag + (size_t)(q*64) * K + k0, &As[cur^1][(q*64 + w*8) * 64]);
        gload_lds16(bg + (size_t)(q*64) * K + k0, &Bs[cur^1][(q*64 + w*8) * 64]);
      }
    }

    bf16x8 af[4][2], blo[2][2], bhi[2][2];
#pragma unroll
    for (int mi = 0; mi < 4; mi++)
#pragma unroll
      for (int kk = 0; kk < 2; kk++) {
        const int row = wm*128 + mi*16 + r16;
        af[mi][kk] = *(const bf16x8*)&As[cur][row*64 + (((kk*4+g) ^ (row & 7)))*8];
      }
#pragma unroll
    for (int ni = 0; ni < 2; ni++)
#pragma unroll
      for (int kk = 0; kk < 2; kk++) {
        const int row = wn*64 + ni*16 + r16;
        blo[ni][kk] = *(const bf16x8*)&Bs[cur][row*64 + (((kk*4+g) ^ (row & 7)))*8];
      }
    __builtin_amdgcn_s_setprio(1);
#pragma unroll
    for (int mi = 0; mi < 4; mi++)
#pragma unroll
      for (int ni = 0; ni < 2; ni++)
#pragma unroll
        for (int kk = 0; kk < 2; kk++)
          acc[mi][ni] = __builtin_amdgcn_mfma_f32_16x16x32_bf16(
              af[mi][kk], blo[ni][kk], acc[mi][ni], 0, 0, 0);
    __builtin_amdgcn_s_setprio(0);
#pragma unroll
    for (int ni = 0; ni < 2; ni++)
#pragma unroll
      for (int kk = 0; kk < 2; kk++) {
        const int row = wn*64 + 32 + ni*16 + r16;
        bhi[ni][kk] = *(const bf16x8*)&Bs[cur][row*64 + (((kk*4+g) ^ (row & 7)))*8];
      }
    __builtin_amdgcn_s_setprio(1);
#pragma unroll
    for (int mi = 0; mi < 4; mi++)
#pragma unroll
      for (int ni = 0; ni < 2; ni++)
#pragma unroll
        for (int kk = 0; kk < 2; kk++)
          acc[mi][2+ni] = __builtin_amdgcn_mfma_f32_16x16x32_bf16(
              af[mi][kk], bhi[ni][kk], acc[mi][2+ni], 0, 0, 0);
    __builtin_amdgcn_s_setprio(0);
#pragma unroll
    for (int mi = 0; mi < 4; mi++)
#pragma unroll
      for (int kk = 0; kk < 2; kk++) {
        const int row = wm*128 + 64 + mi*16 + r16;
        af[mi][kk] = *(const bf16x8*)&As[cur][row*64 + (((kk*4+g) ^ (row & 7)))*8];
      }
    __builtin_amdgcn_s_setprio(1);
#pragma unroll
    for (int mi = 0; mi < 4; mi++)
#pragma unroll
      for (int ni = 0; ni < 2; ni++)
#pragma unroll
        for (int kk = 0; kk < 2; kk++)
          acc[4+mi][2+ni] = __builtin_amdgcn_mfma_f32_16x16x32_bf16(
              af[mi][kk], bhi[ni][kk], acc[4+mi][2+ni], 0, 0, 0);
    __builtin_amdgcn_s_setprio(0);
    __builtin_amdgcn_s_setprio(1);
#pragma unroll
    for (int mi = 0; mi < 4; mi++)
#pragma unroll
      for (int ni = 0; ni < 2; ni++)
#pragma unroll
        for (int kk = 0; kk < 2; kk++)
          acc[4+mi][ni] = __builtin_amdgcn_mfma_f32_16x16x32_bf16(
              af[mi][kk], blo[ni][kk], acc[4+mi][ni], 0, 0, 0);
    __builtin_amdgcn_s_setprio(0);

    asm volatile("s_waitcnt vmcnt(0)" ::: "memory");
    __builtin_amdgcn_s_barrier();
    asm volatile("" ::: "memory");
    cur ^= 1;
  }

  float bvs[4];
#pragma unroll
  for (int ni = 0; ni < 4; ni++) bvs[ni] = bias[n0 + wn*64 + ni*16 + r16];
#pragma unroll
  for (int mi = 0; mi < 8; mi++)
#pragma unroll
    for (int ni = 0; ni < 4; ni++)
#pragma unroll
      for (int r = 0; r < 4; r++) {
        float v = acc[mi][ni][r] + bvs[ni];
        if (RELU) v = fmaxf(v, 0.f);
        C[(size_t)(m0 + wm*128 + mi*16 + g*4 + r) * N +
          (n0 + wn*64 + ni*16 + r16)] = (bf16)v;
      }
}

// ---------------- flash attention: 8 waves x 16 q-rows ----------------
// Round-21 winner + Q pre-scaled by 0.125*log2e at load (removes the
// per-iteration 16 v_mul in the softmax prologue).
__global__ __launch_bounds__(512) void attn(
    const bf16* __restrict__ QKV, const bf16* __restrict__ Vt,
    const float* __restrict__ Mp, bf16* __restrict__ AO) {
  __shared__ bf16 Ks[2][64*64];   // [kv][dh], chunk ^= (kv&7), 16KB
  __shared__ bf16 Vs[2][64*64];   // [dh][kv'], chunk ^= (dh&7), 16KB
  __shared__ bf16 Ps[8][16*72];   // per-wave P, 16 rows, stride 72 (18KB)

  const float SC2 = 0.125f * LOG2E;
  const int bh = blockIdx.x, b = bh >> 4, h = bh & 15;
  const int q0 = blockIdx.y * 128;
  const int tid = threadIdx.x, w = tid >> 6, l = tid & 63;
  const int r16 = l & 15, g = l >> 4;
  const int qw = q0 + w*16;

  bf16x8 qf[2];
#pragma unroll
  for (int kk = 0; kk < 2; kk++) {
    bf16x8 qr = *(const bf16x8*)&QKV[((size_t)(b*S_ + qw + r16))*3072
                                     + h*64 + kk*32 + g*8];
#pragma unroll
    for (int j = 0; j < 8; j++) qf[kk][j] = (bf16)((float)qr[j] * SC2);
  }

  const int srow = w*8 + (l >> 3);
  const int sch  = (l & 7) ^ (l >> 3);
  const bf16* kg = QKV + ((size_t)(b*S_) + srow)*3072 + 1024 + h*64 + sch*8;
  const bf16* vg = Vt + ((size_t)(bh*64 + srow))*S_ + sch*8;

  f32x4 po[4];
#pragma unroll
  for (int n = 0; n < 4; n++) po[n] = (f32x4){0.f,0.f,0.f,0.f};
  float mrun[4], lsum[4];
#pragma unroll
  for (int r = 0; r < 4; r++) { mrun[r] = -1.0e30f; lsum[r] = 0.f; }

  float madd[4];
#pragma unroll
  for (int ct = 0; ct < 4; ct++) madd[ct] = Mp[b*S_ + ct*16 + r16];
  gload_lds16(kg, &Ks[0][w*512]);
  gload_lds16(vg, &Vs[0][w*512]);

  const int NT = S_/64;
  int cur = 0;
  for (int it = 0; it < NT; ++it) {
    const int kv0 = it * 64;
    if (it + 1 < NT) {
      gload_lds16(kg + (size_t)(kv0 + 64)*3072, &Ks[cur^1][w*512]);
      gload_lds16(vg + kv0 + 64,                &Vs[cur^1][w*512]);
      asm volatile("s_waitcnt vmcnt(2)" ::: "memory");
    } else {
      asm volatile("s_waitcnt vmcnt(0)" ::: "memory");
    }
    __builtin_amdgcn_s_barrier();
    asm volatile("" ::: "memory");

    float sv[4][4];
    __builtin_amdgcn_s_setprio(1);
#pragma unroll
    for (int ct = 0; ct < 4; ct++) {
      const int row = ct*16 + r16;
      bf16x8 kf0 = *(const bf16x8*)&Ks[cur][row*64 + ((g) ^ (row & 7))*8];
      bf16x8 kf1 = *(const bf16x8*)&Ks[cur][row*64 + ((4+g) ^ (row & 7))*8];
      f32x4 s = (f32x4){0.f,0.f,0.f,0.f};
      s = __builtin_amdgcn_mfma_f32_16x16x32_bf16(qf[0], kf0, s, 0, 0, 0);
      s = __builtin_amdgcn_mfma_f32_16x16x32_bf16(qf[1], kf1, s, 0, 0, 0);
#pragma unroll
      for (int r = 0; r < 4; r++) sv[ct][r] = s[r] + madd[ct];
    }
    __builtin_amdgcn_s_setprio(0);

    if (it + 1 < NT) {
#pragma unroll
      for (int ct = 0; ct < 4; ct++)
        madd[ct] = Mp[b*S_ + kv0 + 64 + ct*16 + r16];
    }

    float lmax[4];
#pragma unroll
    for (int r = 0; r < 4; r++)
      lmax[r] = fmaxf(fmaxf(sv[0][r], sv[1][r]), fmaxf(sv[2][r], sv[3][r]));
    bool grow = (lmax[0] > mrun[0] + 8.f) | (lmax[1] > mrun[1] + 8.f) |
                (lmax[2] > mrun[2] + 8.f) | (lmax[3] > mrun[3] + 8.f);
    if (__any(grow)) {
#pragma unroll
      for (int r = 0; r < 4; r++) {
        float t = lmax[r];
#pragma unroll
        for (int off = 8; off >= 1; off >>= 1) t = fmaxf(t, __shfl_xor(t, off, 16));
        float mnew = fmaxf(mrun[r], t);
        float sc = fexp2(mrun[r] - mnew);
        mrun[r] = mnew;
        lsum[r] *= sc;
#pragma unroll
        for (int n = 0; n < 4; n++) po[n][r] *= sc;
      }
    }
#pragma unroll
    for (int r = 0; r < 4; r++) {
#pragma unroll
      for (int ct = 0; ct < 4; ct++)
        sv[ct][r] = fexp2(sv[ct][r] - mrun[r]);   // sv becomes P
      lsum[r] += (sv[0][r] + sv[1][r]) + (sv[2][r] + sv[3][r]);
    }

#pragma unroll
    for (int r = 0; r < 4; r++) {
      bf16x4 pk;
#pragma unroll
      for (int ct = 0; ct < 4; ct++) pk[ct] = (bf16)sv[ct][r];
      *(bf16x4*)&Ps[w][(g*4 + r)*72 + r16*4] = pk;
    }
    asm volatile("s_waitcnt lgkmcnt(0)" ::: "memory");

    __builtin_amdgcn_s_setprio(1);
#pragma unroll
    for (int kk = 0; kk < 2; kk++) {
      bf16x8 pa = *(const bf16x8*)&Ps[w][r16*72 + kk*32 + g*8];
#pragma unroll
      for (int n = 0; n < 4; n++) {
        const int row = n*16 + r16;
        bf16x8 vf = *(const bf16x8*)&Vs[cur][row*64 + ((kk*4 + g) ^ (row & 7))*8];
        po[n] = __builtin_amdgcn_mfma_f32_16x16x32_bf16(pa, vf, po[n], 0, 0, 0);
      }
    }
    __builtin_amdgcn_s_setprio(0);

    __builtin_amdgcn_s_barrier();
    asm volatile("" ::: "memory");
    cur ^= 1;
  }

#pragma unroll
  for (int r = 0; r < 4; r++) {
    float t = lsum[r];
#pragma unroll
    for (int off = 8; off >= 1; off >>= 1) t += __shfl_xor(t, off, 16);
    lsum[r] = t;
  }

#pragma unroll
  for (int n = 0; n < 4; n++)
#pragma unroll
    for (int r = 0; r < 4; r++) {
      float v = po[n][r] / lsum[r];
      AO[(size_t)(b*S_ + qw + g*4 + r)*D_ + h*64 + n*16 + r16] = (bf16)v;
    }
}

// ---------------- fused residual + 2-partial bf16 reduce + LayerNorm -------
// Partials are bf16 (halved traffic). In-place bf16 x -> yb is per-row safe.
template<bool OUTF32>
__global__ __launch_bounds__(256) void ln_res2(
    const bf16* __restrict__ xp, const bf16* __restrict__ p0,
    const bf16* __restrict__ p1, const float* __restrict__ sc,
    const float* __restrict__ bi, float* __restrict__ y,
    bf16* __restrict__ yb) {
  const int row = blockIdx.x, tid = threadIdx.x;
  const size_t base = (size_t)row * D_;
  float v[4];
  bf16x4 a = *(const bf16x4*)&xp[base + tid*4];
#pragma unroll
  for (int j = 0; j < 4; j++) v[j] = (float)a[j];
  bf16x4 a0 = *(const bf16x4*)&p0[base + tid*4];
  bf16x4 a1 = *(const bf16x4*)&p1[base + tid*4];
#pragma unroll
  for (int j = 0; j < 4; j++) v[j] += (float)a0[j] + (float)a1[j];
  float s  = v[0] + v[1] + v[2] + v[3];
  float ss = v[0]*v[0] + v[1]*v[1] + v[2]*v[2] + v[3]*v[3];
#pragma unroll
  for (int off = 32; off >= 1; off >>= 1) {
    s  += __shfl_xor(s, off, 64);
    ss += __shfl_xor(ss, off, 64);
  }
  __shared__ float red[8];
  const int wv = tid >> 6;
  if ((tid & 63) == 0) { red[wv] = s; red[4 + wv] = ss; }
  __syncthreads();
  s  = red[0] + red[1] + red[2] + red[3];
  ss = red[4] + red[5] + red[6] + red[7];
  const float mu  = s * (1.0f / D_);
  const float inv = rsqrtf(ss * (1.0f / D_) - mu*mu + 1e-6f);
  float4 scv = ((const float4*)sc)[tid];
  float4 biv = ((const float4*)bi)[tid];
  float o[4];
  o[0] = (v[0]-mu)*inv*scv.x + biv.x;
  o[1] = (v[1]-mu)*inv*scv.y + biv.y;
  o[2] = (v[2]-mu)*inv*scv.z + biv.z;
  o[3] = (v[3]-mu)*inv*scv.w + biv.w;
  if (OUTF32) {
    ((float4*)(y + base))[tid] = make_float4(o[0], o[1], o[2], o[3]);
  } else {
    bf16x4 ob;
#pragma unroll
    for (int j = 0; j < 4; j++) ob[j] = (bf16)o[j];
    *(bf16x4*)&yb[base + tid*4] = ob;
  }
}

// ---------------- launch ----------------
extern "C" void kernel_launch(void* const* d_in, const int* in_sizes, int n_in,
                              void* d_out, int out_size, void* d_ws, size_t ws_size,
                              hipStream_t stream) {
  const float* X    = (const float*)d_in[0];
  const int*   mask = (const int*)d_in[1];
  const float* Wq   = (const float*)d_in[2];
  const float* bq   = (const float*)d_in[3];
  const float* Wk   = (const float*)d_in[4];
  const float* bk   = (const float*)d_in[5];
  const float* Wv   = (const float*)d_in[6];
  const float* bv   = (const float*)d_in[7];
  const float* Wo   = (const float*)d_in[8];
  const float* bo   = (const float*)d_in[9];
  const float* ln0s = (const float*)d_in[10];
  const float* ln0b = (const float*)d_in[11];
  const float* W1   = (const float*)d_in[12];
  const float* b1   = (const float*)d_in[13];
  const float* W2   = (const float*)d_in[14];
  const float* b2   = (const float*)d_in[15];
  const float* ln1s = (const float*)d_in[16];
  const float* ln1b = (const float*)d_in[17];
  float* out = (float*)d_out;

  // workspace layout (96 MB), lifetime-checked reuse:
  //  [0,8)    Xb (residual for ln0) -> X1b (in-place, per-row safe)
  //  [8,16)   Wqkvt(6) + Wot(2)
  //  [16,24)  W1t   [24,32) W2t
  //  [32,64)  QKV(24)+Vt(8); AO at [32,40) after attn; FF1 after Wo gemm
  //  [64,96)  bqkv+Mp (head; dead by Wo gemm) -> 2 x 8MB bf16 partials
  //           (Wo then FF2; dead after each ln)
  char* ws = (char*)d_ws;
  const size_t MB = 1024 * 1024;
  bf16*  Xb    = (bf16*)(ws + 0);        // 8MB, lives until ln0
  bf16*  X1b   = (bf16*)(ws + 0);        // in-place over Xb at ln0
  bf16*  Wqkvt = (bf16*)(ws + 8*MB);     // 6MB  [3072][1024]
  bf16*  Wot   = (bf16*)(ws + 14*MB);    // 2MB  [1024][1024]
  bf16*  W1t   = (bf16*)(ws + 16*MB);    // 8MB  [4096][1024]
  bf16*  W2t   = (bf16*)(ws + 24*MB);    // 8MB  [1024][4096]
  bf16*  QKV   = (bf16*)(ws + 32*MB);    // 24MB [4096][3072]
  bf16*  AO    = (bf16*)(ws + 32*MB);    // 8MB (QKV dead after attn)
  bf16*  Vt    = (bf16*)(ws + 56*MB);    // 8MB  [32][64][2048]
  bf16*  FF1   = (bf16*)(ws + 32*MB);    // 32MB reuse (AO dead after Wo gemm)
  bf16*  Pb    = (bf16*)(ws + 64*MB);    // 2 x 8MB bf16 partials
  float* bqkv  = (float*)(ws + 64*MB);   // 12KB head (dead by Wo gemm)
  float* Mp    = (float*)(ws + 64*MB + 16384);  // 16KB head (dead after attn)

  prep_all<<<PREP_BLOCKS, 256, 0, stream>>>(
      X, Xb, bq, bk, bv, bqkv, mask, Mp,
      Wq, Wk, Wv, Wo, W1, W2, Wqkvt, Wot, W1t, W2t);

  gemm256<false><<<dim3(3072/256, M_/256), 512, 0, stream>>>(Xb, Wqkvt, bqkv, QKV, M_, 3072, D_);
  transpose_v<<<dim3(32, S_/64), 256, 0, stream>>>(QKV, Vt);
  attn<<<dim3(32, S_/128), 512, 0, stream>>>(QKV, Vt, Mp, AO);
  gemm_sk<2,true><<<dim3(D_/128, M_/128, 2), 256, 0, stream>>>(AO, Wot, bo, Pb, M_, D_, D_);
  ln_res2<false><<<M_, 256, 0, stream>>>(Xb, Pb, Pb + (size_t)M_*D_, ln0s, ln0b, nullptr, X1b);
  gemm256<true><<<dim3(FF_/256, M_/256), 512, 0, stream>>>(X1b, W1t, b1, FF1, M_, FF_, D_);
  gemm_sk<2,true><<<dim3(D_/128, M_/128, 2), 256, 0, stream>>>(FF1, W2t, b2, Pb, M_, D_, FF_);
  ln_res2<true><<<M_, 256, 0, stream>>>(X1b, Pb, Pb + (size_t)M_*D_, ln1s, ln1b, out, nullptr);
}